// Round 2
// baseline (2158.025 us; speedup 1.0000x reference)
//
#include <hip/hip_runtime.h>
#include <stdint.h>

// bf16 MFMA fragment types per cdna_hip_programming.md §3
typedef __attribute__((ext_vector_type(8))) short bf16x8;   // 8 bf16 = 4 VGPRs
typedef __attribute__((ext_vector_type(4))) float f32x4;    // C/D for 16x16x32

#define MFMA16(a, b, c) __builtin_amdgcn_mfma_f32_16x16x32_bf16((a), (b), (c), 0, 0, 0)

__device__ __forceinline__ unsigned short f2bf(float f) {
  unsigned int b = __float_as_uint(f);
  b += 0x7FFFu + ((b >> 16) & 1u);   // RNE
  return (unsigned short)(b >> 16);
}
// pack two float4 -> 8 bf16 (RNE)
__device__ __forceinline__ bf16x8 cvt8(const float4 a, const float4 b) {
  bf16x8 r;
  r[0] = (short)f2bf(a.x); r[1] = (short)f2bf(a.y);
  r[2] = (short)f2bf(a.z); r[3] = (short)f2bf(a.w);
  r[4] = (short)f2bf(b.x); r[5] = (short)f2bf(b.y);
  r[6] = (short)f2bf(b.z); r[7] = (short)f2bf(b.w);
  return r;
}
// XOR-swizzled LDS tile index (pitch 512 elems, chunk = 8 elems = 16B).
__device__ __forceinline__ int sw(int row, int chunk) {
  return row * 512 + ((chunk ^ (row & 7)) << 3);
}

// ---------------------------------------------------------------------------
// K1: per-batch fused QKV projection + causal attention. FP32 inputs,
// converted to bf16 at staging/fragment load; fp32 accumulate via MFMA.
// grid = 4096 (one batch), block = 256 (4 waves; wave w handles head hg*4+w).
// Writes Y[b][d][h*32+t] = O_h[t][d] as FP32 into d_out (consumed by K2).
// ---------------------------------------------------------------------------
__global__ __launch_bounds__(256, 2) void qkv_attn_k(
    const float* __restrict__ x,
    const float* __restrict__ wq,
    const float* __restrict__ wk,
    const float* __restrict__ wv,
    float* __restrict__ y) {
  __shared__ __align__(16) unsigned short Xs[32 * 512];       // 32 KB bf16, swizzled
  __shared__ __align__(16) unsigned short Scr[4][3][32 * 40]; // per-wave Q/K/Vt scratch, 30 KB
  const int tid  = threadIdx.x;
  const int lane = tid & 63;
  const int wave = tid >> 6;
  const int m    = lane & 15;   // tile row/col within 16
  const int quad = lane >> 4;   // 0..3
  const int b    = blockIdx.x;

  { // stage X[b] (32 x 512 fp32) into LDS as bf16
    const float* xg = x + (size_t)b * (32 * 512);
#pragma unroll
    for (int i = 0; i < 8; i++) {
      int c = tid + 256 * i;          // 2048 chunks of 8 elems
      int row = c >> 6, ch = c & 63;
      float4 lo = *(const float4*)&xg[row * 512 + ch * 8];
      float4 hi = *(const float4*)&xg[row * 512 + ch * 8 + 4];
      *(bf16x8*)&Xs[sw(row, ch)] = cvt8(lo, hi);
    }
  }
  __syncthreads();

  unsigned short* Qs = &Scr[wave][0][0];  // Q, later re-used for P
  unsigned short* Ks = &Scr[wave][1][0];
  unsigned short* Vt = &Scr[wave][2][0];  // V transposed: Vt[d][s]

  for (int hg = 0; hg < 4; hg++) {
    const int h = hg * 4 + wave;
    // ---- GEMM: Q,K,V [32x32] = X[32x512] @ W_h[32x512]^T, fp32 acc
    f32x4 aq[2][2] = {}; f32x4 ak[2][2] = {}; f32x4 av[2][2] = {};
    const float* qp = wq + (size_t)(h * 32 + m) * 512 + quad * 8;
    const float* kp = wk + (size_t)(h * 32 + m) * 512 + quad * 8;
    const float* vp = wv + (size_t)(h * 32 + m) * 512 + quad * 8;
#pragma unroll 2
    for (int kk = 0; kk < 16; kk++) {
      const int k0 = kk * 32;
      bf16x8 a0 = *(const bf16x8*)&Xs[sw(m, kk * 4 + quad)];       // A[m][k]
      bf16x8 a1 = *(const bf16x8*)&Xs[sw(16 + m, kk * 4 + quad)];
      bf16x8 bq0 = cvt8(*(const float4*)(qp + k0), *(const float4*)(qp + k0 + 4));
      bf16x8 bq1 = cvt8(*(const float4*)(qp + 16 * 512 + k0), *(const float4*)(qp + 16 * 512 + k0 + 4));
      bf16x8 bk0 = cvt8(*(const float4*)(kp + k0), *(const float4*)(kp + k0 + 4));
      bf16x8 bk1 = cvt8(*(const float4*)(kp + 16 * 512 + k0), *(const float4*)(kp + 16 * 512 + k0 + 4));
      bf16x8 bv0 = cvt8(*(const float4*)(vp + k0), *(const float4*)(vp + k0 + 4));
      bf16x8 bv1 = cvt8(*(const float4*)(vp + 16 * 512 + k0), *(const float4*)(vp + 16 * 512 + k0 + 4));
      aq[0][0] = MFMA16(a0, bq0, aq[0][0]);
      aq[1][0] = MFMA16(a1, bq0, aq[1][0]);
      aq[0][1] = MFMA16(a0, bq1, aq[0][1]);
      aq[1][1] = MFMA16(a1, bq1, aq[1][1]);
      ak[0][0] = MFMA16(a0, bk0, ak[0][0]);
      ak[1][0] = MFMA16(a1, bk0, ak[1][0]);
      ak[0][1] = MFMA16(a0, bk1, ak[0][1]);
      ak[1][1] = MFMA16(a1, bk1, ak[1][1]);
      av[0][0] = MFMA16(a0, bv0, av[0][0]);
      av[1][0] = MFMA16(a1, bv0, av[1][0]);
      av[0][1] = MFMA16(a0, bv1, av[0][1]);
      av[1][1] = MFMA16(a1, bv1, av[1][1]);
    }
    // ---- spill Q,K row-major, V transposed (C-layout: row=quad*4+r, col=m)
#pragma unroll
    for (int mi = 0; mi < 2; mi++)
#pragma unroll
      for (int ni = 0; ni < 2; ni++)
#pragma unroll
        for (int r = 0; r < 4; r++) {
          int row = mi * 16 + quad * 4 + r;
          int col = ni * 16 + m;
          Qs[row * 40 + col] = f2bf(aq[mi][ni][r]);
          Ks[row * 40 + col] = f2bf(ak[mi][ni][r]);
          Vt[col * 40 + row] = f2bf(av[mi][ni][r]);
        }
    // ---- S = Q K^T (K-dim = 32 -> single MFMA per 16x16 tile)
    f32x4 sAcc[2][2];
#pragma unroll
    for (int mi = 0; mi < 2; mi++)
#pragma unroll
      for (int ni = 0; ni < 2; ni++) {
        bf16x8 qa = *(const bf16x8*)&Qs[(mi * 16 + m) * 40 + quad * 8];
        bf16x8 kb = *(const bf16x8*)&Ks[(ni * 16 + m) * 40 + quad * 8];
        f32x4 z = {};
        sAcc[mi][ni] = MFMA16(qa, kb, z);
      }
    // ---- causal mask + softmax (row t lives in one 16-lane quad); P -> Qs
    float invs[2][4];
#pragma unroll
    for (int mi = 0; mi < 2; mi++)
#pragma unroll
      for (int r = 0; r < 4; r++) {
        int t = mi * 16 + quad * 4 + r;
        float s0 = sAcc[mi][0][r] * 0.17677669529663687f;  // 1/sqrt(32)
        float s1 = sAcc[mi][1][r] * 0.17677669529663687f;
        s0 = (m <= t) ? s0 : -1e30f;
        s1 = (16 + m <= t) ? s1 : -1e30f;
        float mx = fmaxf(s0, s1);
#pragma unroll
        for (int off = 1; off < 16; off <<= 1) mx = fmaxf(mx, __shfl_xor(mx, off));
        float e0 = __expf(s0 - mx);
        float e1 = __expf(s1 - mx);
        float sm = e0 + e1;
#pragma unroll
        for (int off = 1; off < 16; off <<= 1) sm += __shfl_xor(sm, off);
        invs[mi][r] = 1.0f / sm;           // normalize O after PV (fp32)
        Qs[t * 40 + m] = f2bf(e0);
        Qs[t * 40 + 16 + m] = f2bf(e1);
      }
    // ---- O = P V (unnormalized P, fp32 acc; B operand from Vt rows)
    f32x4 oAcc[2][2];
#pragma unroll
    for (int mi = 0; mi < 2; mi++)
#pragma unroll
      for (int ni = 0; ni < 2; ni++) {
        bf16x8 pa = *(const bf16x8*)&Qs[(mi * 16 + m) * 40 + quad * 8];
        bf16x8 vb = *(const bf16x8*)&Vt[(ni * 16 + m) * 40 + quad * 8];
        f32x4 z = {};
        oAcc[mi][ni] = MFMA16(pa, vb, z);
      }
    // ---- Y[b][d][h*32+t] = O[t][d]/rowsum as FP32; 4 t's per lane -> float4
#pragma unroll
    for (int mi = 0; mi < 2; mi++)
#pragma unroll
      for (int ni = 0; ni < 2; ni++) {
        float4 o;
        o.x = oAcc[mi][ni][0] * invs[mi][0];
        o.y = oAcc[mi][ni][1] * invs[mi][1];
        o.z = oAcc[mi][ni][2] * invs[mi][2];
        o.w = oAcc[mi][ni][3] * invs[mi][3];
        int d = ni * 16 + m;
        int t0 = mi * 16 + quad * 4;
        *(float4*)&y[(size_t)b * 16384 + (size_t)d * 512 + h * 32 + t0] = o;
      }
  }
}

// ---------------------------------------------------------------------------
// K2: Out = Y @ Wp^T + bp, in place on d_out (both fp32, same element size ->
// each block's 64 rows occupy the same bytes read and written; all rows staged
// to LDS before any write). grid = 2048 (BM=64), block = 256; wave owns 128 cols.
// ---------------------------------------------------------------------------
__global__ __launch_bounds__(256, 2) void proj_k(
    float* __restrict__ y,
    const float* __restrict__ wp,
    const float* __restrict__ bp) {
  __shared__ __align__(16) unsigned short Ys[64 * 512];  // 64 KB bf16, swizzled
  const int tid  = threadIdx.x;
  const int lane = tid & 63;
  const int wave = tid >> 6;
  const int m    = lane & 15;
  const int quad = lane >> 4;
  const size_t rbase = (size_t)blockIdx.x * 64;

  { // stage all 64 fp32 Y rows -> bf16 LDS before any write
    const float* yg = y + rbase * 512;
#pragma unroll
    for (int i = 0; i < 16; i++) {
      int c = tid + 256 * i;          // 4096 chunks
      int row = c >> 6, ch = c & 63;
      float4 lo = *(const float4*)&yg[row * 512 + ch * 8];
      float4 hi = *(const float4*)&yg[row * 512 + ch * 8 + 4];
      *(bf16x8*)&Ys[sw(row, ch)] = cvt8(lo, hi);
    }
  }
  __syncthreads();

  const int nb = wave * 128;
  f32x4 acc[4][8] = {};
#pragma unroll 2
  for (int kk = 0; kk < 16; kk++) {
    bf16x8 a[4];
#pragma unroll
    for (int mi = 0; mi < 4; mi++)
      a[mi] = *(const bf16x8*)&Ys[sw(mi * 16 + m, kk * 4 + quad)];
    const int k0 = kk * 32 + quad * 8;
#pragma unroll
    for (int ni = 0; ni < 8; ni++) {
      const float* wrow = wp + (size_t)(nb + ni * 16 + m) * 512 + k0;
      bf16x8 bb = cvt8(*(const float4*)wrow, *(const float4*)(wrow + 4));
#pragma unroll
      for (int mi = 0; mi < 4; mi++) acc[mi][ni] = MFMA16(a[mi], bb, acc[mi][ni]);
    }
  }
  // epilogue: + bp, fp32 store in place
#pragma unroll
  for (int ni = 0; ni < 8; ni++) {
    const int col = nb + ni * 16 + m;
    const float bias = bp[col];
#pragma unroll
    for (int mi = 0; mi < 4; mi++)
#pragma unroll
      for (int r = 0; r < 4; r++) {
        size_t row = rbase + mi * 16 + quad * 4 + r;
        y[row * 512 + col] = acc[mi][ni][r] + bias;
      }
  }
}

extern "C" void kernel_launch(void* const* d_in, const int* in_sizes, int n_in,
                              void* d_out, int out_size, void* d_ws, size_t ws_size,
                              hipStream_t stream) {
  (void)in_sizes; (void)n_in; (void)out_size; (void)d_ws; (void)ws_size;
  const float* x  = (const float*)d_in[0];
  const float* wq = (const float*)d_in[1];
  const float* wk = (const float*)d_in[2];
  const float* wv = (const float*)d_in[3];
  const float* wp = (const float*)d_in[4];
  const float* bp = (const float*)d_in[5];
  float* y = (float*)d_out;

  qkv_attn_k<<<4096, 256, 0, stream>>>(x, wq, wk, wv, y);  // writes fp32 Y into d_out
  proj_k<<<2048, 256, 0, stream>>>(y, wp, bp);             // in-place proj
}

// Round 3
// 1284.884 us; speedup vs baseline: 1.6795x; 1.6795x over previous
//
#include <hip/hip_runtime.h>
#include <stdint.h>

// bf16 MFMA fragment types per cdna_hip_programming.md §3
typedef __attribute__((ext_vector_type(8))) short bf16x8;   // 8 bf16 = 4 VGPRs
typedef __attribute__((ext_vector_type(4))) float f32x4;    // C/D for 16x16x32

#define MFMA16(a, b, c) __builtin_amdgcn_mfma_f32_16x16x32_bf16((a), (b), (c), 0, 0, 0)

__device__ __forceinline__ unsigned short f2bf(float f) {
  unsigned int b = __float_as_uint(f);
  b += 0x7FFFu + ((b >> 16) & 1u);   // RNE
  return (unsigned short)(b >> 16);
}
// pack two float4 -> 8 bf16 (RNE)
__device__ __forceinline__ bf16x8 cvt8(const float4 a, const float4 b) {
  bf16x8 r;
  r[0] = (short)f2bf(a.x); r[1] = (short)f2bf(a.y);
  r[2] = (short)f2bf(a.z); r[3] = (short)f2bf(a.w);
  r[4] = (short)f2bf(b.x); r[5] = (short)f2bf(b.y);
  r[6] = (short)f2bf(b.z); r[7] = (short)f2bf(b.w);
  return r;
}
// weight fragment load: bf16 direct (16B) or fp32 + convert (fallback)
template <bool BF16W>
__device__ __forceinline__ bf16x8 ldw(const void* p, size_t off) {
  if constexpr (BF16W) {
    return *(const bf16x8*)((const unsigned short*)p + off);
  } else {
    const float* f = (const float*)p + off;
    return cvt8(*(const float4*)f, *(const float4*)(f + 4));
  }
}
// XOR-swizzled LDS tile index (pitch 512 elems, chunk = 8 elems = 16B).
__device__ __forceinline__ int sw(int row, int chunk) {
  return row * 512 + ((chunk ^ (row & 7)) << 3);
}

// ---------------------------------------------------------------------------
// K0: convert Wq,Wk,Wv,Wp (each 262144 fp32) -> bf16 into d_ws, contiguous.
// grid = 512 (128 blocks per matrix), block = 256, 8 elems/thread.
// ---------------------------------------------------------------------------
__global__ void cvt_weights_k(const float* __restrict__ wq,
                              const float* __restrict__ wk,
                              const float* __restrict__ wv,
                              const float* __restrict__ wp,
                              unsigned short* __restrict__ dst) {
  const int seg = blockIdx.x >> 7;   // 0..3
  const int blk = blockIdx.x & 127;
  const float* src = (seg == 0) ? wq : (seg == 1) ? wk : (seg == 2) ? wv : wp;
  unsigned short* d = dst + (size_t)seg * 262144;
  const int i = (blk * 256 + threadIdx.x) * 8;
  float4 lo = *(const float4*)&src[i];
  float4 hi = *(const float4*)&src[i + 4];
  *(bf16x8*)&d[i] = cvt8(lo, hi);
}

// ---------------------------------------------------------------------------
// K1: per-batch fused QKV projection + causal attention. FP32 x converted to
// bf16 at staging; weights bf16 (pre-converted) or fp32 (fallback).
// grid = 4096 (one batch), block = 256 (4 waves; wave w handles head hg*4+w).
// Writes Y[b][d][h*32+t] = O_h[t][d] as FP32 into d_out (consumed by K2).
// ---------------------------------------------------------------------------
template <bool BF16W>
__global__ __launch_bounds__(256, 2) void qkv_attn_k(
    const float* __restrict__ x,
    const void* __restrict__ wq,
    const void* __restrict__ wk,
    const void* __restrict__ wv,
    float* __restrict__ y) {
  __shared__ __align__(16) unsigned short Xs[32 * 512];       // 32 KB bf16, swizzled
  __shared__ __align__(16) unsigned short Scr[4][3][32 * 40]; // per-wave Q/K/Vt scratch, 30 KB
  const int tid  = threadIdx.x;
  const int lane = tid & 63;
  const int wave = tid >> 6;
  const int m    = lane & 15;   // tile row/col within 16
  const int quad = lane >> 4;   // 0..3
  const int b    = blockIdx.x;

  { // stage X[b] (32 x 512 fp32) into LDS as bf16
    const float* xg = x + (size_t)b * (32 * 512);
#pragma unroll
    for (int i = 0; i < 8; i++) {
      int c = tid + 256 * i;          // 2048 chunks of 8 elems
      int row = c >> 6, ch = c & 63;
      float4 lo = *(const float4*)&xg[row * 512 + ch * 8];
      float4 hi = *(const float4*)&xg[row * 512 + ch * 8 + 4];
      *(bf16x8*)&Xs[sw(row, ch)] = cvt8(lo, hi);
    }
  }
  __syncthreads();

  unsigned short* Qs = &Scr[wave][0][0];  // Q, later re-used for P
  unsigned short* Ks = &Scr[wave][1][0];
  unsigned short* Vt = &Scr[wave][2][0];  // V transposed: Vt[d][s]

  for (int hg = 0; hg < 4; hg++) {
    const int h = hg * 4 + wave;
    // ---- GEMM: Q,K,V [32x32] = X[32x512] @ W_h[32x512]^T, fp32 acc
    f32x4 aq[2][2] = {}; f32x4 ak[2][2] = {}; f32x4 av[2][2] = {};
    const size_t wbase = (size_t)(h * 32 + m) * 512 + quad * 8;
#pragma unroll 4
    for (int kk = 0; kk < 16; kk++) {
      const int k0 = kk * 32;
      bf16x8 a0 = *(const bf16x8*)&Xs[sw(m, kk * 4 + quad)];       // A[m][k]
      bf16x8 a1 = *(const bf16x8*)&Xs[sw(16 + m, kk * 4 + quad)];
      bf16x8 bq0 = ldw<BF16W>(wq, wbase + k0);
      bf16x8 bq1 = ldw<BF16W>(wq, wbase + 16 * 512 + k0);
      bf16x8 bk0 = ldw<BF16W>(wk, wbase + k0);
      bf16x8 bk1 = ldw<BF16W>(wk, wbase + 16 * 512 + k0);
      bf16x8 bv0 = ldw<BF16W>(wv, wbase + k0);
      bf16x8 bv1 = ldw<BF16W>(wv, wbase + 16 * 512 + k0);
      aq[0][0] = MFMA16(a0, bq0, aq[0][0]);
      aq[1][0] = MFMA16(a1, bq0, aq[1][0]);
      aq[0][1] = MFMA16(a0, bq1, aq[0][1]);
      aq[1][1] = MFMA16(a1, bq1, aq[1][1]);
      ak[0][0] = MFMA16(a0, bk0, ak[0][0]);
      ak[1][0] = MFMA16(a1, bk0, ak[1][0]);
      ak[0][1] = MFMA16(a0, bk1, ak[0][1]);
      ak[1][1] = MFMA16(a1, bk1, ak[1][1]);
      av[0][0] = MFMA16(a0, bv0, av[0][0]);
      av[1][0] = MFMA16(a1, bv0, av[1][0]);
      av[0][1] = MFMA16(a0, bv1, av[0][1]);
      av[1][1] = MFMA16(a1, bv1, av[1][1]);
    }
    // ---- spill Q,K row-major, V transposed (C-layout: row=quad*4+r, col=m)
#pragma unroll
    for (int mi = 0; mi < 2; mi++)
#pragma unroll
      for (int ni = 0; ni < 2; ni++)
#pragma unroll
        for (int r = 0; r < 4; r++) {
          int row = mi * 16 + quad * 4 + r;
          int col = ni * 16 + m;
          Qs[row * 40 + col] = f2bf(aq[mi][ni][r]);
          Ks[row * 40 + col] = f2bf(ak[mi][ni][r]);
          Vt[col * 40 + row] = f2bf(av[mi][ni][r]);
        }
    // ---- S = Q K^T (K-dim = 32 -> single MFMA per 16x16 tile)
    f32x4 sAcc[2][2];
#pragma unroll
    for (int mi = 0; mi < 2; mi++)
#pragma unroll
      for (int ni = 0; ni < 2; ni++) {
        bf16x8 qa = *(const bf16x8*)&Qs[(mi * 16 + m) * 40 + quad * 8];
        bf16x8 kb = *(const bf16x8*)&Ks[(ni * 16 + m) * 40 + quad * 8];
        f32x4 z = {};
        sAcc[mi][ni] = MFMA16(qa, kb, z);
      }
    // ---- causal mask + softmax (row t lives in one 16-lane quad); P -> Qs
    float invs[2][4];
#pragma unroll
    for (int mi = 0; mi < 2; mi++)
#pragma unroll
      for (int r = 0; r < 4; r++) {
        int t = mi * 16 + quad * 4 + r;
        float s0 = sAcc[mi][0][r] * 0.17677669529663687f;  // 1/sqrt(32)
        float s1 = sAcc[mi][1][r] * 0.17677669529663687f;
        s0 = (m <= t) ? s0 : -1e30f;
        s1 = (16 + m <= t) ? s1 : -1e30f;
        float mx = fmaxf(s0, s1);
#pragma unroll
        for (int off = 1; off < 16; off <<= 1) mx = fmaxf(mx, __shfl_xor(mx, off));
        float e0 = __expf(s0 - mx);
        float e1 = __expf(s1 - mx);
        float sm = e0 + e1;
#pragma unroll
        for (int off = 1; off < 16; off <<= 1) sm += __shfl_xor(sm, off);
        invs[mi][r] = 1.0f / sm;           // normalize O after PV (fp32)
        Qs[t * 40 + m] = f2bf(e0);
        Qs[t * 40 + 16 + m] = f2bf(e1);
      }
    // ---- O = P V (unnormalized P, fp32 acc; B operand from Vt rows)
    f32x4 oAcc[2][2];
#pragma unroll
    for (int mi = 0; mi < 2; mi++)
#pragma unroll
      for (int ni = 0; ni < 2; ni++) {
        bf16x8 pa = *(const bf16x8*)&Qs[(mi * 16 + m) * 40 + quad * 8];
        bf16x8 vb = *(const bf16x8*)&Vt[(ni * 16 + m) * 40 + quad * 8];
        f32x4 z = {};
        oAcc[mi][ni] = MFMA16(pa, vb, z);
      }
    // ---- Y[b][d][h*32+t] = O[t][d]/rowsum as FP32; 4 t's per lane -> float4
#pragma unroll
    for (int mi = 0; mi < 2; mi++)
#pragma unroll
      for (int ni = 0; ni < 2; ni++) {
        float4 o;
        o.x = oAcc[mi][ni][0] * invs[mi][0];
        o.y = oAcc[mi][ni][1] * invs[mi][1];
        o.z = oAcc[mi][ni][2] * invs[mi][2];
        o.w = oAcc[mi][ni][3] * invs[mi][3];
        int d = ni * 16 + m;
        int t0 = mi * 16 + quad * 4;
        *(float4*)&y[(size_t)b * 16384 + (size_t)d * 512 + h * 32 + t0] = o;
      }
  }
}

// ---------------------------------------------------------------------------
// K2: Out = Y @ Wp^T + bp, in place on d_out (fp32 Y and out, same bytes ->
// each block stages its full 64 rows to LDS before any write). grid = 2048
// (BM=64), block = 256; wave owns 128 cols.
// ---------------------------------------------------------------------------
template <bool BF16W>
__global__ __launch_bounds__(256, 2) void proj_k(
    float* __restrict__ y,
    const void* __restrict__ wp,
    const float* __restrict__ bp) {
  __shared__ __align__(16) unsigned short Ys[64 * 512];  // 64 KB bf16, swizzled
  const int tid  = threadIdx.x;
  const int lane = tid & 63;
  const int wave = tid >> 6;
  const int m    = lane & 15;
  const int quad = lane >> 4;
  const size_t rbase = (size_t)blockIdx.x * 64;

  { // stage all 64 fp32 Y rows -> bf16 LDS before any write
    const float* yg = y + rbase * 512;
#pragma unroll
    for (int i = 0; i < 16; i++) {
      int c = tid + 256 * i;          // 4096 chunks
      int row = c >> 6, ch = c & 63;
      float4 lo = *(const float4*)&yg[row * 512 + ch * 8];
      float4 hi = *(const float4*)&yg[row * 512 + ch * 8 + 4];
      *(bf16x8*)&Ys[sw(row, ch)] = cvt8(lo, hi);
    }
  }
  __syncthreads();

  const int nb = wave * 128;
  f32x4 acc[4][8] = {};
#pragma unroll 2
  for (int kk = 0; kk < 16; kk++) {
    bf16x8 a[4];
#pragma unroll
    for (int mi = 0; mi < 4; mi++)
      a[mi] = *(const bf16x8*)&Ys[sw(mi * 16 + m, kk * 4 + quad)];
    const int k0 = kk * 32 + quad * 8;
#pragma unroll
    for (int ni = 0; ni < 8; ni++) {
      bf16x8 bb = ldw<BF16W>(wp, (size_t)(nb + ni * 16 + m) * 512 + k0);
#pragma unroll
      for (int mi = 0; mi < 4; mi++) acc[mi][ni] = MFMA16(a[mi], bb, acc[mi][ni]);
    }
  }
  // epilogue: + bp, fp32 store in place
#pragma unroll
  for (int ni = 0; ni < 8; ni++) {
    const int col = nb + ni * 16 + m;
    const float bias = bp[col];
#pragma unroll
    for (int mi = 0; mi < 4; mi++)
#pragma unroll
      for (int r = 0; r < 4; r++) {
        size_t row = rbase + mi * 16 + quad * 4 + r;
        y[row * 512 + col] = acc[mi][ni][r] + bias;
      }
  }
}

extern "C" void kernel_launch(void* const* d_in, const int* in_sizes, int n_in,
                              void* d_out, int out_size, void* d_ws, size_t ws_size,
                              hipStream_t stream) {
  (void)in_sizes; (void)n_in; (void)out_size;
  const float* x  = (const float*)d_in[0];
  const float* wq = (const float*)d_in[1];
  const float* wk = (const float*)d_in[2];
  const float* wv = (const float*)d_in[3];
  const float* wp = (const float*)d_in[4];
  const float* bp = (const float*)d_in[5];
  float* y = (float*)d_out;

  const size_t WE = 262144;  // elems per weight matrix (16*32*512 == 512*512)
  if (ws_size >= 4 * WE * sizeof(unsigned short)) {
    unsigned short* wb = (unsigned short*)d_ws;
    cvt_weights_k<<<512, 256, 0, stream>>>(wq, wk, wv, wp, wb);
    qkv_attn_k<true><<<4096, 256, 0, stream>>>(x, wb, wb + WE, wb + 2 * WE, y);
    proj_k<true><<<2048, 256, 0, stream>>>(y, wb + 3 * WE, bp);
  } else {  // fallback: fp32 weights converted in-loop (R2 path)
    qkv_attn_k<false><<<4096, 256, 0, stream>>>(x, wq, wk, wv, y);
    proj_k<false><<<2048, 256, 0, stream>>>(y, wp, bp);
  }
}